// Round 6
// baseline (524.006 us; speedup 1.0000x reference)
//
#include <hip/hip_runtime.h>

// Problem constants (fixed by the reference)
#define T_TOK 4096   // B*S tokens
#define DIM   1024   // model dim D
#define HID   1024   // expert hidden H
#define NEXP  16     // routed experts
#define HSH   2048   // shared hidden = NSH*H
#define NIN   2      // experts that consume x instead of emb
#define MT_MAX 80    // max routed m-tiles: (8192 + 16*127)/128 rounded up

typedef __attribute__((ext_vector_type(8))) short bf8_t;  // 8 x bf16 (MFMA A/B frag)
typedef __attribute__((ext_vector_type(4))) float f4_t;   // 4 x f32  (MFMA C/D frag)

__device__ __forceinline__ ushort f2b(float f) {  // f32 -> bf16 RNE
  unsigned u = __float_as_uint(f);
  u = (u + 0x7FFFu + ((u >> 16) & 1u)) >> 16;
  return (ushort)u;
}

// ---------------------------------------------------------------------------
// Tile-packed (TP) layout: matrix [NR][NK] stored as 128x64 tiles, row-major
// tile grid (KT = NK/64 tiles per tile-row), 8192 elems (16KB) per tile,
// contiguous. Element (r,c) at r*64 + XOR-swizzled column (by r&7).
// ---------------------------------------------------------------------------
__device__ __forceinline__ int tp_off(int r, int c) {
  return r * 64 + ((((c >> 3) ^ (r & 7)) << 3) | (c & 7));
}
__device__ __forceinline__ size_t tp_idx(int row, int col, int KT) {
  return ((size_t)((row >> 7) * KT + (col >> 6)) << 13) + tp_off(row & 127, col & 63);
}

// Async global->LDS DMA, 16B/lane; LDS dest is wave-uniform base + lane*16.
__device__ __forceinline__ void gl_lds16(const ushort* g, ushort* l) {
  __builtin_amdgcn_global_load_lds(
      (const __attribute__((address_space(1))) void*)g,
      (__attribute__((address_space(3))) void*)l, 16, 0, 0);
}

// ---------------------------------------------------------------------------
// Source offset within a TP [*][64] k-tile for staging a K=32 half-tile:
// dest slot (rd, cp) of half h holds source col-chunk c'' = cp ^ ((rd>>1)&3)
// (dest swizzle -> frag ds_read_b128 is <=2-way bank aliased = free), read
// from source row sr at the source's own TP swizzle (sr&7).
// ---------------------------------------------------------------------------
__device__ __forceinline__ int src_off(int sr, int rd, int cp, int h) {
  const int cg = h * 4 + (cp ^ ((rd >> 1) & 3));
  return sr * 64 + ((cg ^ (sr & 7)) << 3);
}

// ---------------------------------------------------------------------------
// 2-phase double-buffered TP MFMA K-loop (T3 minimum recipe). nkt K=64 tiles
// = 2*nkt K=32 phases. Each phase: issue next half-tile's global_load_lds
// FIRST, then ds_read+MFMA on the current buffer, then __syncthreads (its
// implicit vmcnt(0) lands after a full compute phase of overlap).
// Half-tile LDS = [128][32] (4KB ushorts = 8KB); buffers at +0 / +4096.
// Wave w stages rows [32w,32w+32): d=0 rows +0..15, d=1 rows +16..31; lane
// l covers (row w*32+d*16+(l>>2), chunk l&3) -> dest linear lane*16. Source
// addresses are per-lane (pre-swizzled; supports token-gather for A).
// 4 waves compute 64x64 C-quadrants via 16x16x32 MFMA (quad = k-chunk).
// Data per MFMA is bitwise identical to the old single-buffer version.
// ---------------------------------------------------------------------------
template<bool DUAL>
__device__ __forceinline__ void mfma_tp(
    const ushort* pA00, const ushort* pA01,   // A per-lane src, d=0: h=0 / h=1
    const ushort* pA10, const ushort* pA11,   // A per-lane src, d=1
    const ushort* b1T, const ushort* b3T,     // B tile-row bases
    int oB00, int oB01, int oB10, int oB11,   // B per-lane src offsets
    int nkt, ushort* As, ushort* Bs1, ushort* Bs3,
    f4_t acc1[4][4], f4_t acc3[4][4], int tid)
{
  const int lane = tid & 63, w = tid >> 6;
  const int wm = w & 1, wn = w >> 1;
  const int quad = lane >> 4, lr = lane & 15;
  const int dst0 = w * 1024 + lane * 8;       // ushort index, d=0; d=1: +512

  auto stage = [&](int koff, ushort* dA, ushort* dB1, ushort* dB3,
                   const ushort* a0, const ushort* a1, int ob0, int ob1) {
    gl_lds16(a0 + koff, dA + dst0);
    gl_lds16(a1 + koff, dA + dst0 + 512);
    gl_lds16(b1T + ob0 + koff, dB1 + dst0);
    gl_lds16(b1T + ob1 + koff, dB1 + dst0 + 512);
    if (DUAL) {
      gl_lds16(b3T + ob0 + koff, dB3 + dst0);
      gl_lds16(b3T + ob1 + koff, dB3 + dst0 + 512);
    }
  };
  auto compute = [&](const ushort* A, const ushort* B1, const ushort* B3) {
    bf8_t af[4];
    #pragma unroll
    for (int mi = 0; mi < 4; mi++) {
      const int r = wm * 64 + mi * 16 + lr;
      af[mi] = *(const bf8_t*)&A[r * 32 + ((quad ^ ((r >> 1) & 3)) << 3)];
    }
    #pragma unroll
    for (int ni = 0; ni < 4; ni++) {
      const int n = wn * 64 + ni * 16 + lr;
      const bf8_t b1 = *(const bf8_t*)&B1[n * 32 + ((quad ^ ((n >> 1) & 3)) << 3)];
      #pragma unroll
      for (int mi = 0; mi < 4; mi++)
        acc1[mi][ni] = __builtin_amdgcn_mfma_f32_16x16x32_bf16(af[mi], b1, acc1[mi][ni], 0, 0, 0);
      if (DUAL) {
        const bf8_t b3 = *(const bf8_t*)&B3[n * 32 + ((quad ^ ((n >> 1) & 3)) << 3)];
        #pragma unroll
        for (int mi = 0; mi < 4; mi++)
          acc3[mi][ni] = __builtin_amdgcn_mfma_f32_16x16x32_bf16(af[mi], b3, acc3[mi][ni], 0, 0, 0);
      }
    }
  };

  // prologue: stage (kt=0, h=0) into buf0
  stage(0, As, Bs1, Bs3, pA00, pA10, oB00, oB10);
  __syncthreads();
  for (int kt = 0; kt < nkt; kt++) {
    const int ko = kt << 13;                  // kt * 8192
    // phase h=0: prefetch (kt,1) -> buf1; compute buf0
    stage(ko, As + 4096, Bs1 + 4096, Bs3 + 4096, pA01, pA11, oB01, oB11);
    compute(As, Bs1, Bs3);
    __syncthreads();
    // phase h=1: prefetch (kt+1,0) -> buf0; compute buf1
    if (kt + 1 < nkt)
      stage(ko + 8192, As, Bs1, Bs3, pA00, pA10, oB00, oB10);
    compute(As + 4096, Bs1 + 4096, Bs3 + 4096);
    __syncthreads();
  }
}

// ---------------------------------------------------------------------------
// ONE-CHUNK band transpose+cast+TP-pack (LDS pad dropped: stride 256 so
// 5 blocks/CU fit). Phase A: contiguous 1KB row reads -> bf16 LDS, 8B chunks
// XOR-swizzled by (r>>3)&7. Phase B: (n,kc) gather, wave stores cover 1KB
// contiguous TP.
// ---------------------------------------------------------------------------
__device__ __forceinline__ void tr_chunk(const float* __restrict__ src,
                                         ushort* __restrict__ dst,
                                         int R, int C, int band, int c, int tid,
                                         ushort* ts)
{
  const int KT = R >> 6;
  const int k0 = band * 64;
  #pragma unroll
  for (int i = 0; i < 16; i++) {
    const int idx = i * 256 + tid;          // 0..4095
    const int r = idx >> 6, c4 = idx & 63;  // row, float4-col
    const float4 v = *(const float4*)(src + (size_t)(k0 + r) * C + c * 256 + c4 * 4);
    ushort4 u;
    u.x = f2b(v.x); u.y = f2b(v.y); u.z = f2b(v.z); u.w = f2b(v.w);
    *(ushort4*)&ts[r * 256 + ((c4 ^ ((r >> 3) & 7)) << 2)] = u;
  }
  __syncthreads();
  #pragma unroll
  for (int s = 0; s < 8; s++) {
    const int idx = s * 256 + tid;          // 0..2047 = 256 n x 8 kc
    const int n = idx >> 3, kc = idx & 7;
    ushort o[8];
    #pragma unroll
    for (int j = 0; j < 8; j++)
      o[j] = ts[(kc * 8 + j) * 256 + (((n >> 2) ^ kc) << 2) + (n & 3)];
    *(uint4*)&dst[tp_idx(c * 256 + n, k0 + kc * 8, KT)] = *(uint4*)o;
  }
}

// ---------------------------------------------------------------------------
// MEGA-PREP flat dispatch (heavy transpose blocks FIRST):
//   [0,3072)        W1/W3/W2: 48 slices x 16 bands x 4 chunks
//   [3072,3200)     sW1 (R=1024,C=2048): 16 bands x 8 chunks
//   [3200,3328)     sW2 (R=2048,C=1024): 32 bands x 4 chunks
//   [3328,4352)     gate: wave-parallel softmax+top2, 1 wave = 1 token
//   [4352,4864)     cast emb->etp, x->xtp
// ---------------------------------------------------------------------------
#define PREP_BLOCKS 4864
__launch_bounds__(256, 5)
__global__ void prep(const float* __restrict__ emb, const float* __restrict__ x_,
                     const float* __restrict__ gw,
                     const float* __restrict__ W1, const float* __restrict__ W3,
                     const float* __restrict__ W2,
                     const float* __restrict__ sW1, const float* __restrict__ sW2,
                     ushort* __restrict__ etp, ushort* __restrict__ xtp,
                     ushort* __restrict__ w1tp, ushort* __restrict__ w3tp,
                     ushort* __restrict__ w2tp,
                     ushort* __restrict__ sw1tp, ushort* __restrict__ sw2tp,
                     int* __restrict__ eA, int* __restrict__ eB,
                     float* __restrict__ wA, float* __restrict__ wB)
{
  __shared__ ushort ts[64 * 256];   // 32768 B -> 5 blocks/CU
  const int b = blockIdx.x;
  const int t = threadIdx.x;

  if (b < 3328) {
    const float* src; ushort* dst; int R, C, band, chunk;
    if (b < 3072) {
      const int z = b >> 6, rem = b & 63;        // slice 0..47
      band = rem >> 2; chunk = rem & 3;
      const int e = z & 15;
      src = ((z < 16) ? W1 : (z < 32) ? W3 : W2) + ((size_t)e << 20);
      dst = ((z < 16) ? w1tp : (z < 32) ? w3tp : w2tp) + ((size_t)e << 20);
      R = 1024; C = 1024;
    } else if (b < 3200) {
      const int i = b - 3072; band = i >> 3; chunk = i & 7;
      src = sW1; dst = sw1tp; R = 1024; C = 2048;
    } else {
      const int i = b - 3200; band = i >> 2; chunk = i & 3;
      src = sW2; dst = sw2tp; R = 2048; C = 1024;
    }
    tr_chunk(src, dst, R, C, band, chunk, t, ts);
  } else if (b < 4352) {
    // ---- gate: 1 wave = 1 token; all loads 1KB-contiguous per instruction.
    const int w = t >> 6, lane = t & 63;
    const int tok = (b - 3328) * 4 + w;
    const float* er = emb + (size_t)tok * DIM + lane * 4;
    const float4 a0 = *(const float4*)(er);
    const float4 a1 = *(const float4*)(er + 256);
    const float4 a2 = *(const float4*)(er + 512);
    const float4 a3 = *(const float4*)(er + 768);
    float pe[NEXP];
    #pragma unroll
    for (int e = 0; e < NEXP; e++) {
      const float* gr = gw + (size_t)e * DIM + lane * 4;
      const float4 g0 = *(const float4*)(gr);
      const float4 g1 = *(const float4*)(gr + 256);
      const float4 g2 = *(const float4*)(gr + 512);
      const float4 g3 = *(const float4*)(gr + 768);
      float p = a0.x * g0.x + a0.y * g0.y + a0.z * g0.z + a0.w * g0.w;
      p += a1.x * g1.x + a1.y * g1.y + a1.z * g1.z + a1.w * g1.w;
      p += a2.x * g2.x + a2.y * g2.y + a2.z * g2.z + a2.w * g2.w;
      p += a3.x * g3.x + a3.y * g3.y + a3.z * g3.z + a3.w * g3.w;
      pe[e] = p;
    }
    #pragma unroll
    for (int e = 0; e < NEXP; e++) {
      float v = pe[e];
      v += __shfl_xor(v, 1);  v += __shfl_xor(v, 2);
      v += __shfl_xor(v, 4);  v += __shfl_xor(v, 8);
      v += __shfl_xor(v, 16); v += __shfl_xor(v, 32);
      pe[e] = v;
    }
    if (lane == 0) {
      float m1 = pe[0];
      #pragma unroll
      for (int j = 1; j < NEXP; j++) m1 = fmaxf(m1, pe[j]);
      float sum = 0.f;
      #pragma unroll
      for (int j = 0; j < NEXP; j++) sum += __expf(pe[j] - m1);
      int i0 = 0; float b0 = pe[0];
      #pragma unroll
      for (int j = 1; j < NEXP; j++) if (pe[j] > b0) { b0 = pe[j]; i0 = j; }
      int i1 = -1; float b1 = -3.402823466e38f;
      #pragma unroll
      for (int j = 0; j < NEXP; j++) if (j != i0 && pe[j] > b1) { b1 = pe[j]; i1 = j; }
      const float inv = 1.0f / sum;
      eA[tok] = i0; wA[tok] = __expf(b0 - m1) * inv;
      eB[tok] = i1; wB[tok] = __expf(b1 - m1) * inv;
    }
  } else {
    // ---------------- cast emb/x -> TP bf16 ----------------
    const int NC = (T_TOK * DIM) / 8;
    const int c0 = (b - 4352) * 256 + t;
    for (int c = c0; c < 2 * NC; c += 512 * 256) {
      const bool isE = c < NC;
      const int g = (isE ? c : c - NC) << 3;
      const float* src = isE ? emb : x_;
      const float4 v0 = *(const float4*)(src + g);
      const float4 v1 = *(const float4*)(src + g + 4);
      ushort tt[8];
      tt[0] = f2b(v0.x); tt[1] = f2b(v0.y); tt[2] = f2b(v0.z); tt[3] = f2b(v0.w);
      tt[4] = f2b(v1.x); tt[5] = f2b(v1.y); tt[6] = f2b(v1.z); tt[7] = f2b(v1.w);
      const int row = g >> 10, col = g & 1023;
      ushort* dst = isE ? etp : xtp;
      *(uint4*)&dst[tp_idx(row, col, 16)] = *(uint4*)tt;
    }
  }
}

// ---------------------------------------------------------------------------
// Build per-expert compact lists from per-token top-2 (deterministic).
// ---------------------------------------------------------------------------
__global__ void build_lists(const int* __restrict__ eA, const int* __restrict__ eB,
                            const float* __restrict__ wA, const float* __restrict__ wB,
                            int* __restrict__ cnt, int* __restrict__ list,
                            float* __restrict__ wl)
{
  const int e = blockIdx.x;
  __shared__ int wsum[4];
  __shared__ int sbase;
  const int tid = threadIdx.x;
  const int lane = tid & 63, wv = tid >> 6;
  if (tid == 0) sbase = 0;
  __syncthreads();
  for (int r = 0; r < 16; r++) {
    const int tk = r * 256 + tid;
    const int a = eA[tk], bb = eB[tk];
    const bool m = (a == e) || (bb == e);
    const float w = (a == e) ? wA[tk] : wB[tk];
    const unsigned long long bal = __ballot(m);
    const int pw = __popcll(bal & ((1ULL << lane) - 1ULL));
    if (lane == 63) wsum[wv] = pw + (m ? 1 : 0);
    __syncthreads();
    int base = sbase;
    for (int k = 0; k < wv; k++) base += wsum[k];
    if (m) {
      const int pos = base + pw;
      list[e * T_TOK + pos] = tk;
      wl[e * T_TOK + pos] = w;
    }
    __syncthreads();
    if (tid == 0) sbase += wsum[0] + wsum[1] + wsum[2] + wsum[3];
    __syncthreads();
  }
  if (tid == 0) cnt[e] = sbase;
}

// offp[e] = 128-aligned prefix sum; offp[17] = #m-tiles; tbl[2*mt] = {e, row0}
__global__ void scan_offs(const int* __restrict__ cnt, int* __restrict__ offp,
                          int* __restrict__ tbl)
{
  if (blockIdx.x == 0 && threadIdx.x == 0) {
    int a = 0, nm = 0;
    for (int e = 0; e < NEXP; e++) {
      offp[e] = a;
      const int c = (cnt[e] + 127) & ~127;
      for (int r = 0; r < c; r += 128) { tbl[2 * nm] = e; tbl[2 * nm + 1] = a + r; nm++; }
      a += c;
    }
    offp[NEXP] = a;
    offp[NEXP + 1] = nm;
  }
}

// ---------------------------------------------------------------------------
// Stage 1, flat grid: b < 512 -> shared front (hs TP); else routed SwiGLU
// front (h TP). Routed A is token-GATHERED directly in staging (per-lane
// global src addresses) — no separate gather kernel. Pad rows clamp to a
// valid token; M-rows are independent and pads are masked downstream.
// ---------------------------------------------------------------------------
__launch_bounds__(256, 3)
__global__ void stage1(const ushort* __restrict__ etp, const ushort* __restrict__ xtp,
                       const ushort* __restrict__ w1tp, const ushort* __restrict__ w3tp,
                       const ushort* __restrict__ sw1tp,
                       const float* __restrict__ B1, const float* __restrict__ B3,
                       const float* __restrict__ sB1,
                       const int* __restrict__ cnt, const int* __restrict__ offp,
                       const int* __restrict__ tbl, const int* __restrict__ list,
                       ushort* __restrict__ h_tp, ushort* __restrict__ hs_tp)
{
  __shared__ ushort As[8192], Bs1[8192], Bs3[8192];
  const int tid = threadIdx.x;
  const int lane = tid & 63, w = tid >> 6;
  const int wm = w & 1, wn = w >> 1;
  const int quad = lane >> 4, lr = lane & 15;
  const int r0 = w * 32 + (lane >> 2), r1 = r0 + 16, cp = lane & 3;
  const int b = blockIdx.x;

  f4_t acc1[4][4], acc3[4][4];
  const f4_t fz = {0.f, 0.f, 0.f, 0.f};
  #pragma unroll
  for (int i = 0; i < 4; i++)
    #pragma unroll
    for (int j = 0; j < 4; j++) { acc1[i][j] = fz; acc3[i][j] = fz; }

  const int o00 = src_off(r0, r0, cp, 0), o01 = src_off(r0, r0, cp, 1);
  const int o10 = src_off(r1, r1, cp, 0), o11 = src_off(r1, r1, cp, 1);

  if (b < 512) {                       // ---- shared expert front: all real
    const int m0 = (b >> 4) << 7;
    const int n0 = (b & 15) << 7;
    const ushort* aT = etp + ((size_t)((m0 >> 7) * 16) << 13);
    const ushort* bT = sw1tp + ((size_t)((n0 >> 7) * 16) << 13);
    mfma_tp<false>(aT + o00, aT + o01, aT + o10, aT + o11,
                   bT, nullptr, o00, o01, o10, o11,
                   16, As, Bs1, Bs3, acc1, acc3, tid);
    #pragma unroll
    for (int mi = 0; mi < 4; mi++) {
      #pragma unroll
      for (int r = 0; r < 4; r++) {
        const int row = m0 + wm * 64 + mi * 16 + quad * 4 + r;
        #pragma unroll
        for (int ni = 0; ni < 4; ni++) {
          const int col = n0 + wn * 64 + ni * 16 + lr;
          const float v = acc1[mi][ni][r] + sB1[col];
          const float sg = 1.0f / (1.0f + __expf(-v));
          hs_tp[tp_idx(row, col, 32)] = f2b(v * sg);
        }
      }
    }
  } else {                             // ---- routed SwiGLU front
    const int t = b - 512;
    const int mt = t >> 3;
    if (mt >= offp[NEXP + 1]) return;
    const int n0 = (t & 7) << 7;
    const int e = tbl[2 * mt], row0 = tbl[2 * mt + 1];
    const int ce = cnt[e];
    const int s0 = row0 - offp[e];
    const ushort* src = (e < NIN) ? xtp : etp;
    int sa = s0 + r0; if (sa >= ce) sa = ce - 1;
    int sb = s0 + r1; if (sb >= ce) sb = ce - 1;
    const int tokA = list[e * T_TOK + sa];
    const int tokB = list[e * T_TOK + sb];
    const ushort* tA = src + ((size_t)((tokA >> 7) * 16) << 13);
    const ushort* tB = src + ((size_t)((tokB >> 7) * 16) << 13);
    const int ra = tokA & 127, rb = tokB & 127;
    const ushort* b1T = w1tp + ((size_t)e << 20) + ((size_t)((n0 >> 7) * 16) << 13);
    const ushort* b3T = w3tp + ((size_t)e << 20) + ((size_t)((n0 >> 7) * 16) << 13);
    mfma_tp<true>(tA + src_off(ra, r0, cp, 0), tA + src_off(ra, r0, cp, 1),
                  tB + src_off(rb, r1, cp, 0), tB + src_off(rb, r1, cp, 1),
                  b1T, b3T, o00, o01, o10, o11,
                  16, As, Bs1, Bs3, acc1, acc3, tid);
    #pragma unroll
    for (int mi = 0; mi < 4; mi++) {
      #pragma unroll
      for (int r = 0; r < 4; r++) {
        const int grow = row0 + wm * 64 + mi * 16 + quad * 4 + r;
        #pragma unroll
        for (int ni = 0; ni < 4; ni++) {
          const int col = n0 + wn * 64 + ni * 16 + lr;
          const float v1 = acc1[mi][ni][r] + B1[e * HID + col];
          const float v3 = acc3[mi][ni][r] + B3[e * HID + col];
          const float sg = 1.0f / (1.0f + __expf(-v1));
          h_tp[tp_idx(grow, col, 16)] = f2b(v1 * sg * v3);
        }
      }
    }
  }
}

// ---------------------------------------------------------------------------
// Stage 2, flat grid: b < 256 -> shared back; else routed back. Both
// atomicAdd into zero-inited y.
// ---------------------------------------------------------------------------
__launch_bounds__(256, 4)
__global__ void stage2(const ushort* __restrict__ h_tp, const ushort* __restrict__ hs_tp,
                       const ushort* __restrict__ w2tp, const ushort* __restrict__ sw2tp,
                       const float* __restrict__ B2, const float* __restrict__ sB2,
                       const int* __restrict__ cnt, const int* __restrict__ offp,
                       const int* __restrict__ tbl, const int* __restrict__ list,
                       const float* __restrict__ wl, float* __restrict__ y)
{
  __shared__ ushort As[8192], Bs[8192];
  const int tid = threadIdx.x;
  const int lane = tid & 63, w = tid >> 6;
  const int wm = w & 1, wn = w >> 1;
  const int quad = lane >> 4, lr = lane & 15;
  const int r0 = w * 32 + (lane >> 2), r1 = r0 + 16, cp = lane & 3;
  const int b = blockIdx.x;

  f4_t acc[4][4];
  const f4_t fz = {0.f, 0.f, 0.f, 0.f};
  #pragma unroll
  for (int i = 0; i < 4; i++)
    #pragma unroll
    for (int j = 0; j < 4; j++) acc[i][j] = fz;

  const int o00 = src_off(r0, r0, cp, 0), o01 = src_off(r0, r0, cp, 1);
  const int o10 = src_off(r1, r1, cp, 0), o11 = src_off(r1, r1, cp, 1);

  if (b < 256) {                       // ---- shared expert back (K=2048)
    const int m0 = (b >> 3) << 7;
    const int n0 = (b & 7) << 7;
    const ushort* aT = hs_tp + ((size_t)((m0 >> 7) * 32) << 13);
    const ushort* bT = sw2tp + ((size_t)((n0 >> 7) * 32) << 13);
    mfma_tp<false>(aT + o00, aT + o01, aT + o10, aT + o11,
                   bT, nullptr, o00, o01, o10, o11,
                   32, As, Bs, Bs, acc, acc, tid);
    #pragma unroll
    for (int mi = 0; mi < 4; mi++) {
      #pragma unroll
      for (int r = 0; r < 4; r++) {
        const int row = m0 + wm * 64 + mi * 16 + quad * 4 + r;
        float* yr = y + (size_t)row * DIM;
        #pragma unroll
        for (int ni = 0; ni < 4; ni++) {
          const int col = n0 + wn * 64 + ni * 16 + lr;
          atomicAdd(&yr[col], acc[mi][ni][r] + sB2[col]);
        }
      }
    }
  } else {                             // ---- routed back (K=1024)
    const int t = b - 256;
    const int mt = t >> 3;
    if (mt >= offp[NEXP + 1]) return;
    const int n0 = (t & 7) << 7;
    const int e = tbl[2 * mt], row0 = tbl[2 * mt + 1];
    const int ce = cnt[e];
    const int s0 = row0 - offp[e];
    const ushort* aT = h_tp + ((size_t)((row0 >> 7) * 16) << 13);
    const ushort* bT = w2tp + ((size_t)e << 20) + ((size_t)((n0 >> 7) * 16) << 13);
    mfma_tp<false>(aT + o00, aT + o01, aT + o10, aT + o11,
                   bT, nullptr, o00, o01, o10, o11,
                   16, As, Bs, Bs, acc, acc, tid);
    #pragma unroll
    for (int mi = 0; mi < 4; mi++) {
      #pragma unroll
      for (int r = 0; r < 4; r++) {
        const int rowl = s0 + wm * 64 + mi * 16 + quad * 4 + r;
        if (rowl < ce) {
          const int tok = list[e * T_TOK + rowl];
          const float wgt = wl[e * T_TOK + rowl];
          float* yr = y + (size_t)tok * DIM;
          #pragma unroll
          for (int ni = 0; ni < 4; ni++) {
            const int col = n0 + wn * 64 + ni * 16 + lr;
            atomicAdd(&yr[col], wgt * (acc[mi][ni][r] + B2[e * DIM + col]));
          }
        }
      }
    }
  }
}

// ---------------------------------------------------------------------------
// Launch
// ---------------------------------------------------------------------------
extern "C" void kernel_launch(void* const* d_in, const int* in_sizes, int n_in,
                              void* d_out, int out_size, void* d_ws, size_t ws_size,
                              hipStream_t stream)
{
  const float* emb = (const float*)d_in[0];
  const float* x   = (const float*)d_in[1];
  const float* gw  = (const float*)d_in[2];
  const float* W1  = (const float*)d_in[3];
  const float* B1  = (const float*)d_in[4];
  const float* W2  = (const float*)d_in[5];
  const float* B2  = (const float*)d_in[6];
  const float* W3  = (const float*)d_in[7];
  const float* B3  = (const float*)d_in[8];
  const float* sW1 = (const float*)d_in[9];
  const float* sB1 = (const float*)d_in[10];
  const float* sW2 = (const float*)d_in[11];
  const float* sB2 = (const float*)d_in[12];
  float* y = (float*)d_out;

  char* ws = (char*)d_ws;
  const size_t MB = 1024ULL * 1024ULL;
  ushort* xtp   = (ushort*)(ws + 0);        // x TP (KT=16)
  ushort* etp   = (ushort*)(ws + 16 * MB);  // emb TP (KT=16)
  ushort* w1tp  = (ushort*)(ws + 24 * MB);  // [16] x TP [1024n][1024k]
  ushort* w3tp  = (ushort*)(ws + 56 * MB);
  ushort* w2tp  = (ushort*)(ws + 88 * MB);  // [16] x TP [1024n][1024k]
  ushort* sw1tp = (ushort*)(ws + 120 * MB); // TP [2048n][1024k]
  ushort* sw2tp = (ushort*)(ws + 124 * MB); // TP [1024n][2048k]
  ushort* h_tp  = (ushort*)(ws + 148 * MB); // routed hidden, TP, <=10240 rows
  ushort* hs_tp = (ushort*)(ws + 168 * MB); // shared hidden, TP [4096][2048]
  int*   cnt    = (int*)(ws + 184 * MB);    // [16]
  int*   offp   = cnt + 16;                 // [18]  (offp[17] = #m-tiles)
  int*   tbl    = offp + 18;                // [2*MT_MAX]
  int*   list   = (int*)(ws + 184 * MB + 1024);            // [16][4096]
  float* wl     = (float*)(ws + 184 * MB + 1024 + 262144); // [16][4096]
  int*   eA     = (int*)(ws + 185 * MB);    // [4096]
  int*   eB     = eA + T_TOK;
  float* wA     = (float*)(eB + T_TOK);
  float* wB     = wA + T_TOK;

  hipMemsetAsync(y, 0, (size_t)T_TOK * DIM * sizeof(float), stream);
  prep<<<PREP_BLOCKS, 256, 0, stream>>>(emb, x, gw, W1, W3, W2, sW1, sW2,
                                        etp, xtp, w1tp, w3tp, w2tp,
                                        sw1tp, sw2tp, eA, eB, wA, wB);
  build_lists<<<NEXP, 256, 0, stream>>>(eA, eB, wA, wB, cnt, list, wl);
  scan_offs<<<1, 64, 0, stream>>>(cnt, offp, tbl);
  stage1<<<512 + MT_MAX * 8, 256, 0, stream>>>(etp, xtp, w1tp, w3tp, sw1tp,
                                               B1, B3, sB1, cnt, offp, tbl, list,
                                               h_tp, hs_tp);
  stage2<<<256 + MT_MAX * 8, 256, 0, stream>>>(h_tp, hs_tp, w2tp, sw2tp, B2, sB2,
                                               cnt, offp, tbl, list, wl, y);
}

// Round 8
// 474.958 us; speedup vs baseline: 1.1033x; 1.1033x over previous
//
#include <hip/hip_runtime.h>

// Problem constants (fixed by the reference)
#define T_TOK 4096   // B*S tokens
#define DIM   1024   // model dim D
#define HID   1024   // expert hidden H
#define NEXP  16     // routed experts
#define HSH   2048   // shared hidden = NSH*H
#define NIN   2      // experts that consume x instead of emb
#define MT_MAX 80    // max routed m-tiles

typedef __attribute__((ext_vector_type(8))) short bf8_t;  // 8 x bf16 (MFMA A/B frag)
typedef __attribute__((ext_vector_type(4))) float f4_t;   // 4 x f32  (MFMA C/D frag)

__device__ __forceinline__ ushort f2b(float f) {  // f32 -> bf16 RNE
  unsigned u = __float_as_uint(f);
  u = (u + 0x7FFFu + ((u >> 16) & 1u)) >> 16;
  return (ushort)u;
}

// ---------------------------------------------------------------------------
// Tile-packed (TP) layout, K=32 half-tiles: matrix [NR][NK] stored as 128x32
// tiles (4096 elems = 8KB), row-major tile grid (KT = NK/32). Row-PAIR
// swizzle: combined row R=r>>1 holds 8 16B slots; even row r in slots 0-3,
// odd row in slots 4-7; chunk position = (chunk ^ (R&3)) | ((r&1)<<2).
// => a row's 4 chunks are ONE contiguous 64B segment (L2-merged even when
// internally permuted); verbatim tile copies are fully linear; MFMA frag
// ds_read_b128 is <=2-way bank-aliased (free).
// ---------------------------------------------------------------------------
__device__ __forceinline__ int tp_off(int r, int c) {   // r<128, c<32
  const int R2 = r >> 1;
  return (R2 << 6) + ((((((c >> 3) ^ R2) & 3)) | ((r & 1) << 2)) << 3) + (c & 7);
}
__device__ __forceinline__ size_t tp_idx(int row, int col, int KT) {  // KT = NK/32
  return ((size_t)((row >> 7) * KT + (col >> 5)) << 12) + tp_off(row & 127, col & 31);
}
// Per-lane source offset for gathering row sr's logical chunk cl (one 16B):
__device__ __forceinline__ int srcA(int sr, int cl) {
  const int S2 = sr >> 1;
  return (S2 << 6) + (((((cl ^ S2) & 3)) | ((sr & 1) << 2)) << 3);
}

// Async global->LDS DMA, 16B/lane; LDS dest is wave-uniform base + lane*16.
__device__ __forceinline__ void gl_lds16(const ushort* g, ushort* l) {
  __builtin_amdgcn_global_load_lds(
      (const __attribute__((address_space(1))) void*)g,
      (__attribute__((address_space(3))) void*)l, 16, 0, 0);
}

// ---------------------------------------------------------------------------
// 2-phase double-buffered TP MFMA K-loop. nph K=32 phases; per phase: issue
// next half-tile's global_load_lds FIRST, compute current buffer, barrier
// (its implicit vmcnt(0) lands after a full compute phase of overlap).
// Buffers: 4096-ushort halves of each 8192-ushort LDS array.
// Per phase per wave: 2 A + 2 B1 (+2 B3) gl_lds16; dest linear (w*1024 +
// d*512 + lane*8 ushorts) -> dest slot (row rd=w*32+d*16+(lane>>2), holding
// logical chunk cl=(lane&3)^((lane>>3)&3) per the row-pair swizzle).
// Sources advance +4096 elems per phase (consecutive k-tiles, contiguous).
// 4 waves compute 64x64 C-quadrants via 16x16x32 MFMA (quad = k-chunk).
// ---------------------------------------------------------------------------
template<bool DUAL>
__device__ __forceinline__ void mfma_tp(
    const ushort* pA0, const ushort* pA1,   // per-lane A src, d=0 / d=1 rows
    const ushort* pB1, const ushort* pB3,   // per-lane B src (verbatim: base+dl)
    int nph, ushort* As, ushort* Bs1, ushort* Bs3,
    f4_t acc1[4][4], f4_t acc3[4][4], int tid)
{
  const int lane = tid & 63, w = tid >> 6;
  const int wm = w & 1, wn = w >> 1;
  const int quad = lane >> 4, lr = lane & 15;
  const int d0 = w * 1024 + lane * 8;

  auto stage = [&](int po, ushort* dA, ushort* dB1, ushort* dB3) {
    gl_lds16(pA0 + po, dA + d0);
    gl_lds16(pA1 + po, dA + d0 + 512);
    gl_lds16(pB1 + po, dB1 + d0);
    gl_lds16(pB1 + po + 512, dB1 + d0 + 512);
    if (DUAL) {
      gl_lds16(pB3 + po, dB3 + d0);
      gl_lds16(pB3 + po + 512, dB3 + d0 + 512);
    }
  };
  auto compute = [&](const ushort* A, const ushort* B1, const ushort* B3) {
    bf8_t af[4];
    #pragma unroll
    for (int mi = 0; mi < 4; mi++) {
      const int r = wm * 64 + mi * 16 + lr;
      const int R2 = r >> 1;
      af[mi] = *(const bf8_t*)&A[(R2 << 6) + ((((quad ^ R2) & 3) | ((r & 1) << 2)) << 3)];
    }
    #pragma unroll
    for (int ni = 0; ni < 4; ni++) {
      const int n = wn * 64 + ni * 16 + lr;
      const int N2 = n >> 1;
      const int bo = (N2 << 6) + ((((quad ^ N2) & 3) | ((n & 1) << 2)) << 3);
      const bf8_t b1 = *(const bf8_t*)&B1[bo];
      #pragma unroll
      for (int mi = 0; mi < 4; mi++)
        acc1[mi][ni] = __builtin_amdgcn_mfma_f32_16x16x32_bf16(af[mi], b1, acc1[mi][ni], 0, 0, 0);
      if (DUAL) {
        const bf8_t b3 = *(const bf8_t*)&B3[bo];
        #pragma unroll
        for (int mi = 0; mi < 4; mi++)
          acc3[mi][ni] = __builtin_amdgcn_mfma_f32_16x16x32_bf16(af[mi], b3, acc3[mi][ni], 0, 0, 0);
      }
    }
  };

  stage(0, As, Bs1, Bs3);
  __syncthreads();
  for (int ph = 0; ph < nph; ph++) {
    const int cur = (ph & 1) << 12;        // 0 or 4096
    const int nxt = cur ^ 4096;
    if (ph + 1 < nph)
      stage((ph + 1) << 12, As + nxt, Bs1 + nxt, Bs3 + nxt);
    compute(As + cur, Bs1 + cur, Bs3 + cur);
    __syncthreads();
  }
}

// ---------------------------------------------------------------------------
// ONE-CHUNK band transpose+cast+TP-pack (Round-4-proven form: LDS stride 264,
// 4 blocks/CU). Phase A: contiguous 1KB row reads -> bf16 LDS, 8B chunks
// XOR-swizzled by (r>>3)&7. Phase B: (n,kc) gather of 8 u16, wave stores
// cover contiguous TP regions (16B stores merged within 64B row segments).
// ---------------------------------------------------------------------------
__device__ __forceinline__ void tr_chunk(const float* __restrict__ src,
                                         ushort* __restrict__ dst,
                                         int R, int C, int band, int c, int tid,
                                         ushort* ts)
{
  const int KT = R >> 5;
  const int k0 = band * 64;
  #pragma unroll
  for (int i = 0; i < 16; i++) {
    const int idx = i * 256 + tid;          // 0..4095
    const int r = idx >> 6, c4 = idx & 63;  // row, float4-col
    const float4 v = *(const float4*)(src + (size_t)(k0 + r) * C + c * 256 + c4 * 4);
    ushort4 u;
    u.x = f2b(v.x); u.y = f2b(v.y); u.z = f2b(v.z); u.w = f2b(v.w);
    *(ushort4*)&ts[r * 264 + ((c4 ^ ((r >> 3) & 7)) << 2)] = u;
  }
  __syncthreads();
  #pragma unroll
  for (int s = 0; s < 8; s++) {
    const int idx = s * 256 + tid;          // 0..2047 = 256 n x 8 kc
    const int n = idx >> 3, kc = idx & 7;
    ushort o[8];
    #pragma unroll
    for (int j = 0; j < 8; j++)
      o[j] = ts[(kc * 8 + j) * 264 + (((n >> 2) ^ kc) << 2) + (n & 3)];
    *(uint4*)&dst[tp_idx(c * 256 + n, k0 + kc * 8, KT)] = *(uint4*)o;
  }
}

// ---------------------------------------------------------------------------
// MEGA-PREP flat dispatch (heavy transpose blocks FIRST):
//   [0,3072)        W1/W3/W2: 48 slices x 16 bands x 4 chunks
//   [3072,3200)     sW1 (R=1024,C=2048): 16 bands x 8 chunks
//   [3200,3328)     sW2 (R=2048,C=1024): 32 bands x 4 chunks
//   [3328,4352)     gate: wave-parallel softmax+top2, 1 wave = 1 token
//   [4352,4864)     cast emb->etp, x->xtp
// ---------------------------------------------------------------------------
#define PREP_BLOCKS 4864
__launch_bounds__(256, 4)
__global__ void prep(const float* __restrict__ emb, const float* __restrict__ x_,
                     const float* __restrict__ gw,
                     const float* __restrict__ W1, const float* __restrict__ W3,
                     const float* __restrict__ W2,
                     const float* __restrict__ sW1, const float* __restrict__ sW2,
                     ushort* __restrict__ etp, ushort* __restrict__ xtp,
                     ushort* __restrict__ w1tp, ushort* __restrict__ w3tp,
                     ushort* __restrict__ w2tp,
                     ushort* __restrict__ sw1tp, ushort* __restrict__ sw2tp,
                     int* __restrict__ eA, int* __restrict__ eB,
                     float* __restrict__ wA, float* __restrict__ wB)
{
  __shared__ ushort ts[64 * 264];   // 33792 B
  const int b = blockIdx.x;
  const int t = threadIdx.x;

  if (b < 3328) {
    const float* src; ushort* dst; int R, C, band, chunk;
    if (b < 3072) {
      const int z = b >> 6, rem = b & 63;        // slice 0..47
      band = rem >> 2; chunk = rem & 3;
      const int e = z & 15;
      src = ((z < 16) ? W1 : (z < 32) ? W3 : W2) + ((size_t)e << 20);
      dst = ((z < 16) ? w1tp : (z < 32) ? w3tp : w2tp) + ((size_t)e << 20);
      R = 1024; C = 1024;
    } else if (b < 3200) {
      const int i = b - 3072; band = i >> 3; chunk = i & 7;
      src = sW1; dst = sw1tp; R = 1024; C = 2048;
    } else {
      const int i = b - 3200; band = i >> 2; chunk = i & 3;
      src = sW2; dst = sw2tp; R = 2048; C = 1024;
    }
    tr_chunk(src, dst, R, C, band, chunk, t, ts);
  } else if (b < 4352) {
    // ---- gate: 1 wave = 1 token; all loads 1KB-contiguous per instruction.
    const int w = t >> 6, lane = t & 63;
    const int tok = (b - 3328) * 4 + w;
    const float* er = emb + (size_t)tok * DIM + lane * 4;
    const float4 a0 = *(const float4*)(er);
    const float4 a1 = *(const float4*)(er + 256);
    const float4 a2 = *(const float4*)(er + 512);
    const float4 a3 = *(const float4*)(er + 768);
    float pe[NEXP];
    #pragma unroll
    for (int e = 0; e < NEXP; e++) {
      const float* gr = gw + (size_t)e * DIM + lane * 4;
      const float4 g0 = *(const float4*)(gr);
      const float4 g1 = *(const float4*)(gr + 256);
      const float4 g2 = *(const float4*)(gr + 512);
      const float4 g3 = *(const float4*)(gr + 768);
      float p = a0.x * g0.x + a0.y * g0.y + a0.z * g0.z + a0.w * g0.w;
      p += a1.x * g1.x + a1.y * g1.y + a1.z * g1.z + a1.w * g1.w;
      p += a2.x * g2.x + a2.y * g2.y + a2.z * g2.z + a2.w * g2.w;
      p += a3.x * g3.x + a3.y * g3.y + a3.z * g3.z + a3.w * g3.w;
      pe[e] = p;
    }
    #pragma unroll
    for (int e = 0; e < NEXP; e++) {
      float v = pe[e];
      v += __shfl_xor(v, 1);  v += __shfl_xor(v, 2);
      v += __shfl_xor(v, 4);  v += __shfl_xor(v, 8);
      v += __shfl_xor(v, 16); v += __shfl_xor(v, 32);
      pe[e] = v;
    }
    if (lane == 0) {
      float m1 = pe[0];
      #pragma unroll
      for (int j = 1; j < NEXP; j++) m1 = fmaxf(m1, pe[j]);
      float sum = 0.f;
      #pragma unroll
      for (int j = 0; j < NEXP; j++) sum += __expf(pe[j] - m1);
      int i0 = 0; float b0 = pe[0];
      #pragma unroll
      for (int j = 1; j < NEXP; j++) if (pe[j] > b0) { b0 = pe[j]; i0 = j; }
      int i1 = -1; float b1 = -3.402823466e38f;
      #pragma unroll
      for (int j = 0; j < NEXP; j++) if (j != i0 && pe[j] > b1) { b1 = pe[j]; i1 = j; }
      const float inv = 1.0f / sum;
      eA[tok] = i0; wA[tok] = __expf(b0 - m1) * inv;
      eB[tok] = i1; wB[tok] = __expf(b1 - m1) * inv;
    }
  } else {
    // ---------------- cast emb/x -> TP bf16 ----------------
    const int NC = (T_TOK * DIM) / 8;
    const int c0 = (b - 4352) * 256 + t;
    for (int c = c0; c < 2 * NC; c += 512 * 256) {
      const bool isE = c < NC;
      const int g = (isE ? c : c - NC) << 3;
      const float* src = isE ? emb : x_;
      const float4 v0 = *(const float4*)(src + g);
      const float4 v1 = *(const float4*)(src + g + 4);
      ushort tt[8];
      tt[0] = f2b(v0.x); tt[1] = f2b(v0.y); tt[2] = f2b(v0.z); tt[3] = f2b(v0.w);
      tt[4] = f2b(v1.x); tt[5] = f2b(v1.y); tt[6] = f2b(v1.z); tt[7] = f2b(v1.w);
      const int row = g >> 10, col = g & 1023;
      ushort* dst = isE ? etp : xtp;
      *(uint4*)&dst[tp_idx(row, col, 32)] = *(uint4*)tt;
    }
  }
}

// ---------------------------------------------------------------------------
// Build per-expert compact lists from per-token top-2 (deterministic).
// ---------------------------------------------------------------------------
__global__ void build_lists(const int* __restrict__ eA, const int* __restrict__ eB,
                            const float* __restrict__ wA, const float* __restrict__ wB,
                            int* __restrict__ cnt, int* __restrict__ list,
                            float* __restrict__ wl)
{
  const int e = blockIdx.x;
  __shared__ int wsum[4];
  __shared__ int sbase;
  const int tid = threadIdx.x;
  const int lane = tid & 63, wv = tid >> 6;
  if (tid == 0) sbase = 0;
  __syncthreads();
  for (int r = 0; r < 16; r++) {
    const int tk = r * 256 + tid;
    const int a = eA[tk], bb = eB[tk];
    const bool m = (a == e) || (bb == e);
    const float w = (a == e) ? wA[tk] : wB[tk];
    const unsigned long long bal = __ballot(m);
    const int pw = __popcll(bal & ((1ULL << lane) - 1ULL));
    if (lane == 63) wsum[wv] = pw + (m ? 1 : 0);
    __syncthreads();
    int base = sbase;
    for (int k = 0; k < wv; k++) base += wsum[k];
    if (m) {
      const int pos = base + pw;
      list[e * T_TOK + pos] = tk;
      wl[e * T_TOK + pos] = w;
    }
    __syncthreads();
    if (tid == 0) sbase += wsum[0] + wsum[1] + wsum[2] + wsum[3];
    __syncthreads();
  }
  if (tid == 0) cnt[e] = sbase;
}

// offp[e] = 128-aligned prefix sum; offp[17] = #m-tiles; tbl[2*mt] = {e, row0}
__global__ void scan_offs(const int* __restrict__ cnt, int* __restrict__ offp,
                          int* __restrict__ tbl)
{
  if (blockIdx.x == 0 && threadIdx.x == 0) {
    int a = 0, nm = 0;
    for (int e = 0; e < NEXP; e++) {
      offp[e] = a;
      const int c = (cnt[e] + 127) & ~127;
      for (int r = 0; r < c; r += 128) { tbl[2 * nm] = e; tbl[2 * nm + 1] = a + r; nm++; }
      a += c;
    }
    offp[NEXP] = a;
    offp[NEXP + 1] = nm;
  }
}

// ---------------------------------------------------------------------------
// Stage 1, flat grid: b < 512 -> shared front (hs TP); else routed SwiGLU
// front (h TP). Routed A is token-GATHERED in staging: per-lane source =
// token tile + srcA(row, cl) -- each row's 4 chunks are one 64B line, so
// gather reads coalesce like a verbatim copy. Pad rows clamp to a valid
// token; pads masked downstream by rowl<ce.
// ---------------------------------------------------------------------------
__launch_bounds__(256, 3)
__global__ void stage1(const ushort* __restrict__ etp, const ushort* __restrict__ xtp,
                       const ushort* __restrict__ w1tp, const ushort* __restrict__ w3tp,
                       const ushort* __restrict__ sw1tp,
                       const float* __restrict__ B1, const float* __restrict__ B3,
                       const float* __restrict__ sB1,
                       const int* __restrict__ cnt, const int* __restrict__ offp,
                       const int* __restrict__ tbl, const int* __restrict__ list,
                       ushort* __restrict__ h_tp, ushort* __restrict__ hs_tp)
{
  __shared__ ushort As[8192], Bs1[8192], Bs3[8192];
  const int tid = threadIdx.x;
  const int lane = tid & 63, w = tid >> 6;
  const int wm = w & 1, wn = w >> 1;
  const int quad = lane >> 4, lr = lane & 15;
  const int rd0 = w * 32 + (lane >> 2), rd1 = rd0 + 16;
  const int cl = (lane & 3) ^ ((lane >> 3) & 3);   // logical chunk this lane stages
  const int dl = w * 1024 + lane * 8;              // verbatim per-lane offset
  const int b = blockIdx.x;

  f4_t acc1[4][4], acc3[4][4];
  const f4_t fz = {0.f, 0.f, 0.f, 0.f};
  #pragma unroll
  for (int i = 0; i < 4; i++)
    #pragma unroll
    for (int j = 0; j < 4; j++) { acc1[i][j] = fz; acc3[i][j] = fz; }

  if (b < 512) {                       // ---- shared expert front: all real
    const int m0 = (b >> 4) << 7;
    const int n0 = (b & 15) << 7;
    const ushort* aT = etp + (((size_t)(m0 >> 7) * 32) << 12);
    const ushort* bT = sw1tp + (((size_t)(n0 >> 7) * 32) << 12);
    mfma_tp<false>(aT + dl, aT + dl + 512, bT + dl, nullptr,
                   32, As, Bs1, Bs3, acc1, acc3, tid);
    #pragma unroll
    for (int mi = 0; mi < 4; mi++) {
      #pragma unroll
      for (int r = 0; r < 4; r++) {
        const int row = m0 + wm * 64 + mi * 16 + quad * 4 + r;
        #pragma unroll
        for (int ni = 0; ni < 4; ni++) {
          const int col = n0 + wn * 64 + ni * 16 + lr;
          const float v = acc1[mi][ni][r] + sB1[col];
          const float sg = 1.0f / (1.0f + __expf(-v));
          hs_tp[tp_idx(row, col, 64)] = f2b(v * sg);
        }
      }
    }
  } else {                             // ---- routed SwiGLU front
    const int t = b - 512;
    const int mt = t >> 3;
    if (mt >= offp[NEXP + 1]) return;
    const int n0 = (t & 7) << 7;
    const int e = tbl[2 * mt], row0 = tbl[2 * mt + 1];
    const int ce = cnt[e];
    const int s0 = row0 - offp[e];
    const ushort* src = (e < NIN) ? xtp : etp;
    int sa = s0 + rd0; if (sa >= ce) sa = ce - 1;
    int sb = s0 + rd1; if (sb >= ce) sb = ce - 1;
    const int tokA = list[e * T_TOK + sa];
    const int tokB = list[e * T_TOK + sb];
    const ushort* pA0 = src + (((size_t)(tokA >> 7) * 32) << 12) + srcA(tokA & 127, cl);
    const ushort* pA1 = src + (((size_t)(tokB >> 7) * 32) << 12) + srcA(tokB & 127, cl);
    const ushort* b1T = w1tp + ((size_t)e << 20) + (((size_t)(n0 >> 7) * 32) << 12);
    const ushort* b3T = w3tp + ((size_t)e << 20) + (((size_t)(n0 >> 7) * 32) << 12);
    mfma_tp<true>(pA0, pA1, b1T + dl, b3T + dl,
                  32, As, Bs1, Bs3, acc1, acc3, tid);
    #pragma unroll
    for (int mi = 0; mi < 4; mi++) {
      #pragma unroll
      for (int r = 0; r < 4; r++) {
        const int grow = row0 + wm * 64 + mi * 16 + quad * 4 + r;
        #pragma unroll
        for (int ni = 0; ni < 4; ni++) {
          const int col = n0 + wn * 64 + ni * 16 + lr;
          const float v1 = acc1[mi][ni][r] + B1[e * HID + col];
          const float v3 = acc3[mi][ni][r] + B3[e * HID + col];
          const float sg = 1.0f / (1.0f + __expf(-v1));
          h_tp[tp_idx(grow, col, 32)] = f2b(v1 * sg * v3);
        }
      }
    }
  }
}

// ---------------------------------------------------------------------------
// Stage 2, flat grid: b < 256 -> shared back; else routed back. Both
// atomicAdd into zero-inited y.
// ---------------------------------------------------------------------------
__launch_bounds__(256, 4)
__global__ void stage2(const ushort* __restrict__ h_tp, const ushort* __restrict__ hs_tp,
                       const ushort* __restrict__ w2tp, const ushort* __restrict__ sw2tp,
                       const float* __restrict__ B2, const float* __restrict__ sB2,
                       const int* __restrict__ cnt, const int* __restrict__ offp,
                       const int* __restrict__ tbl, const int* __restrict__ list,
                       const float* __restrict__ wl, float* __restrict__ y)
{
  __shared__ ushort As[8192], Bs[8192];
  const int tid = threadIdx.x;
  const int lane = tid & 63, w = tid >> 6;
  const int wm = w & 1, wn = w >> 1;
  const int quad = lane >> 4, lr = lane & 15;
  const int dl = w * 1024 + lane * 8;
  const int b = blockIdx.x;

  f4_t acc[4][4];
  const f4_t fz = {0.f, 0.f, 0.f, 0.f};
  #pragma unroll
  for (int i = 0; i < 4; i++)
    #pragma unroll
    for (int j = 0; j < 4; j++) acc[i][j] = fz;

  if (b < 256) {                       // ---- shared expert back (K=2048)
    const int m0 = (b >> 3) << 7;
    const int n0 = (b & 7) << 7;
    const ushort* aT = hs_tp + (((size_t)(m0 >> 7) * 64) << 12);
    const ushort* bT = sw2tp + (((size_t)(n0 >> 7) * 64) << 12);
    mfma_tp<false>(aT + dl, aT + dl + 512, bT + dl, nullptr,
                   64, As, Bs, Bs, acc, acc, tid);
    #pragma unroll
    for (int mi = 0; mi < 4; mi++) {
      #pragma unroll
      for (int r = 0; r < 4; r++) {
        const int row = m0 + wm * 64 + mi * 16 + quad * 4 + r;
        float* yr = y + (size_t)row * DIM;
        #pragma unroll
        for (int ni = 0; ni < 4; ni++) {
          const int col = n0 + wn * 64 + ni * 16 + lr;
          atomicAdd(&yr[col], acc[mi][ni][r] + sB2[col]);
        }
      }
    }
  } else {                             // ---- routed back (K=1024)
    const int t = b - 256;
    const int mt = t >> 3;
    if (mt >= offp[NEXP + 1]) return;
    const int n0 = (t & 7) << 7;
    const int e = tbl[2 * mt], row0 = tbl[2 * mt + 1];
    const int ce = cnt[e];
    const int s0 = row0 - offp[e];
    const ushort* aT = h_tp + (((size_t)(row0 >> 7) * 32) << 12);
    const ushort* bT = w2tp + ((size_t)e << 20) + (((size_t)(n0 >> 7) * 32) << 12);
    mfma_tp<false>(aT + dl, aT + dl + 512, bT + dl, nullptr,
                   32, As, Bs, Bs, acc, acc, tid);
    #pragma unroll
    for (int mi = 0; mi < 4; mi++) {
      #pragma unroll
      for (int r = 0; r < 4; r++) {
        const int rowl = s0 + wm * 64 + mi * 16 + quad * 4 + r;
        if (rowl < ce) {
          const int tok = list[e * T_TOK + rowl];
          const float wgt = wl[e * T_TOK + rowl];
          float* yr = y + (size_t)tok * DIM;
          #pragma unroll
          for (int ni = 0; ni < 4; ni++) {
            const int col = n0 + wn * 64 + ni * 16 + lr;
            atomicAdd(&yr[col], wgt * (acc[mi][ni][r] + B2[e * DIM + col]));
          }
        }
      }
    }
  }
}

// ---------------------------------------------------------------------------
// Launch
// ---------------------------------------------------------------------------
extern "C" void kernel_launch(void* const* d_in, const int* in_sizes, int n_in,
                              void* d_out, int out_size, void* d_ws, size_t ws_size,
                              hipStream_t stream)
{
  const float* emb = (const float*)d_in[0];
  const float* x   = (const float*)d_in[1];
  const float* gw  = (const float*)d_in[2];
  const float* W1  = (const float*)d_in[3];
  const float* B1  = (const float*)d_in[4];
  const float* W2  = (const float*)d_in[5];
  const float* B2  = (const float*)d_in[6];
  const float* W3  = (const float*)d_in[7];
  const float* B3  = (const float*)d_in[8];
  const float* sW1 = (const float*)d_in[9];
  const float* sB1 = (const float*)d_in[10];
  const float* sW2 = (const float*)d_in[11];
  const float* sB2 = (const float*)d_in[12];
  float* y = (float*)d_out;

  char* ws = (char*)d_ws;
  const size_t MB = 1024ULL * 1024ULL;
  ushort* xtp   = (ushort*)(ws + 0);        // x TP (KT=32)
  ushort* etp   = (ushort*)(ws + 16 * MB);  // emb TP (KT=32)
  ushort* w1tp  = (ushort*)(ws + 24 * MB);  // [16] x TP [1024n][1024k]
  ushort* w3tp  = (ushort*)(ws + 56 * MB);
  ushort* w2tp  = (ushort*)(ws + 88 * MB);  // [16] x TP [1024n][1024k]
  ushort* sw1tp = (ushort*)(ws + 120 * MB); // TP [2048n][1024k]
  ushort* sw2tp = (ushort*)(ws + 124 * MB); // TP [1024n][2048k]
  ushort* h_tp  = (ushort*)(ws + 148 * MB); // routed hidden, TP, <=10240 rows
  ushort* hs_tp = (ushort*)(ws + 168 * MB); // shared hidden, TP [4096][2048]
  int*   cnt    = (int*)(ws + 184 * MB);    // [16]
  int*   offp   = cnt + 16;                 // [18]  (offp[17] = #m-tiles)
  int*   tbl    = offp + 18;                // [2*MT_MAX]
  int*   list   = (int*)(ws + 184 * MB + 1024);            // [16][4096]
  float* wl     = (float*)(ws + 184 * MB + 1024 + 262144); // [16][4096]
  int*   eA     = (int*)(ws + 185 * MB);    // [4096]
  int*   eB     = eA + T_TOK;
  float* wA     = (float*)(eB + T_TOK);
  float* wB     = wA + T_TOK;

  hipMemsetAsync(y, 0, (size_t)T_TOK * DIM * sizeof(float), stream);
  prep<<<PREP_BLOCKS, 256, 0, stream>>>(emb, x, gw, W1, W3, W2, sW1, sW2,
                                        etp, xtp, w1tp, w3tp, w2tp,
                                        sw1tp, sw2tp, eA, eB, wA, wB);
  build_lists<<<NEXP, 256, 0, stream>>>(eA, eB, wA, wB, cnt, list, wl);
  scan_offs<<<1, 64, 0, stream>>>(cnt, offp, tbl);
  stage1<<<512 + MT_MAX * 8, 256, 0, stream>>>(etp, xtp, w1tp, w3tp, sw1tp,
                                               B1, B3, sB1, cnt, offp, tbl, list,
                                               h_tp, hs_tp);
  stage2<<<256 + MT_MAX * 8, 256, 0, stream>>>(h_tp, hs_tp, w2tp, sw2tp, B2, sB2,
                                               cnt, offp, tbl, list, wl, y);
}

// Round 9
// 459.320 us; speedup vs baseline: 1.1408x; 1.0340x over previous
//
#include <hip/hip_runtime.h>

// Problem constants (fixed by the reference)
#define T_TOK 4096   // B*S tokens
#define DIM   1024   // model dim D
#define HID   1024   // expert hidden H
#define NEXP  16     // routed experts
#define HSH   2048   // shared hidden = NSH*H
#define NIN   2      // experts that consume x instead of emb
#define MT_MAX 80    // max routed m-tiles

typedef __attribute__((ext_vector_type(8))) short bf8_t;  // 8 x bf16 (MFMA A/B frag)
typedef __attribute__((ext_vector_type(4))) float f4_t;   // 4 x f32  (MFMA C/D frag)

__device__ __forceinline__ ushort f2b(float f) {  // f32 -> bf16 RNE
  unsigned u = __float_as_uint(f);
  u = (u + 0x7FFFu + ((u >> 16) & 1u)) >> 16;
  return (ushort)u;
}

// ---------------------------------------------------------------------------
// Tile-packed (TP) layout, K=32 half-tiles: matrix [NR][NK] stored as 128x32
// tiles (4096 elems = 8KB), row-major tile grid (KT = NK/32). Row-PAIR
// swizzle: combined row R=r>>1 holds 8 16B slots; even row r in slots 0-3,
// odd row in slots 4-7; chunk position = (chunk ^ (R&3)) | ((r&1)<<2).
// => a row's 4 chunks are ONE contiguous 64B segment (L2-merged even when
// internally permuted); verbatim tile copies are fully linear; MFMA frag
// ds_read_b128 is <=2-way bank-aliased (free).
// ---------------------------------------------------------------------------
__device__ __forceinline__ int tp_off(int r, int c) {   // r<128, c<32
  const int R2 = r >> 1;
  return (R2 << 6) + ((((((c >> 3) ^ R2) & 3)) | ((r & 1) << 2)) << 3) + (c & 7);
}
__device__ __forceinline__ size_t tp_idx(int row, int col, int KT) {  // KT = NK/32
  return ((size_t)((row >> 7) * KT + (col >> 5)) << 12) + tp_off(row & 127, col & 31);
}
// Per-lane source offset for gathering row sr's logical chunk cl (one 16B):
__device__ __forceinline__ int srcA(int sr, int cl) {
  const int S2 = sr >> 1;
  return (S2 << 6) + (((((cl ^ S2) & 3)) | ((sr & 1) << 2)) << 3);
}

// Async global->LDS DMA, 16B/lane; LDS dest is wave-uniform base + lane*16.
__device__ __forceinline__ void gl_lds16(const ushort* g, ushort* l) {
  __builtin_amdgcn_global_load_lds(
      (const __attribute__((address_space(1))) void*)g,
      (__attribute__((address_space(3))) void*)l, 16, 0, 0);
}

// ---------------------------------------------------------------------------
// 2-phase double-buffered TP MFMA K-loop. nph K=32 phases; per phase: issue
// next half-tile's global_load_lds FIRST, compute current buffer, barrier
// (its implicit vmcnt(0) lands after a full compute phase of overlap).
// Buffers: 4096-ushort halves of each 8192-ushort LDS array.
// Per phase per wave: 2 A + 2 B1 (+2 B3) gl_lds16; dest linear (w*1024 +
// d*512 + lane*8 ushorts) -> dest slot (row rd=w*32+d*16+(lane>>2), holding
// logical chunk cl=(lane&3)^((lane>>3)&3) per the row-pair swizzle).
// Sources advance +4096 elems per phase (consecutive k-tiles, contiguous).
// 4 waves compute 64x64 C-quadrants via 16x16x32 MFMA (quad = k-chunk).
// ---------------------------------------------------------------------------
template<bool DUAL>
__device__ __forceinline__ void mfma_tp(
    const ushort* pA0, const ushort* pA1,   // per-lane A src, d=0 / d=1 rows
    const ushort* pB1, const ushort* pB3,   // per-lane B src (verbatim: base+dl)
    int nph, ushort* As, ushort* Bs1, ushort* Bs3,
    f4_t acc1[4][4], f4_t acc3[4][4], int tid)
{
  const int lane = tid & 63, w = tid >> 6;
  const int wm = w & 1, wn = w >> 1;
  const int quad = lane >> 4, lr = lane & 15;
  const int d0 = w * 1024 + lane * 8;

  auto stage = [&](int po, ushort* dA, ushort* dB1, ushort* dB3) {
    gl_lds16(pA0 + po, dA + d0);
    gl_lds16(pA1 + po, dA + d0 + 512);
    gl_lds16(pB1 + po, dB1 + d0);
    gl_lds16(pB1 + po + 512, dB1 + d0 + 512);
    if (DUAL) {
      gl_lds16(pB3 + po, dB3 + d0);
      gl_lds16(pB3 + po + 512, dB3 + d0 + 512);
    }
  };
  auto compute = [&](const ushort* A, const ushort* B1, const ushort* B3) {
    bf8_t af[4];
    #pragma unroll
    for (int mi = 0; mi < 4; mi++) {
      const int r = wm * 64 + mi * 16 + lr;
      const int R2 = r >> 1;
      af[mi] = *(const bf8_t*)&A[(R2 << 6) + ((((quad ^ R2) & 3) | ((r & 1) << 2)) << 3)];
    }
    #pragma unroll
    for (int ni = 0; ni < 4; ni++) {
      const int n = wn * 64 + ni * 16 + lr;
      const int N2 = n >> 1;
      const int bo = (N2 << 6) + ((((quad ^ N2) & 3) | ((n & 1) << 2)) << 3);
      const bf8_t b1 = *(const bf8_t*)&B1[bo];
      #pragma unroll
      for (int mi = 0; mi < 4; mi++)
        acc1[mi][ni] = __builtin_amdgcn_mfma_f32_16x16x32_bf16(af[mi], b1, acc1[mi][ni], 0, 0, 0);
      if (DUAL) {
        const bf8_t b3 = *(const bf8_t*)&B3[bo];
        #pragma unroll
        for (int mi = 0; mi < 4; mi++)
          acc3[mi][ni] = __builtin_amdgcn_mfma_f32_16x16x32_bf16(af[mi], b3, acc3[mi][ni], 0, 0, 0);
      }
    }
  };

  stage(0, As, Bs1, Bs3);
  __syncthreads();
  for (int ph = 0; ph < nph; ph++) {
    const int cur = (ph & 1) << 12;        // 0 or 4096
    const int nxt = cur ^ 4096;
    if (ph + 1 < nph)
      stage((ph + 1) << 12, As + nxt, Bs1 + nxt, Bs3 + nxt);
    compute(As + cur, Bs1 + cur, Bs3 + cur);
    __syncthreads();
  }
}

// ---------------------------------------------------------------------------
// 32-ROW chunk transpose+cast+TP-pack: chunk = 32 k-rows (ONE K=32 tile
// depth) x 256 n-cols. LDS 32x264 u16 = 16.9KB -> 8 blocks/CU (2x the old
// 64-row version's occupancy; latency-bound regime). Phase A: contiguous
// 1KB row reads -> bf16 LDS, 8B chunks XOR-swizzled by (r>>3)&3. Phase B:
// (n,kc) gather of 8 u16; wave (16 n x 4 kc) stores 16 consecutive rows'
// 64B segments = 1KB contiguous TP per instruction.
// ---------------------------------------------------------------------------
__device__ __forceinline__ void tr_chunk(const float* __restrict__ src,
                                         ushort* __restrict__ dst,
                                         int R, int C, int band, int c, int tid,
                                         ushort* ts)
{
  const int KT = R >> 5;
  const int k0 = band * 32;
  #pragma unroll
  for (int i = 0; i < 8; i++) {
    const int idx = i * 256 + tid;          // 0..2047
    const int r = idx >> 6, c4 = idx & 63;  // row 0..31, float4-col
    const float4 v = *(const float4*)(src + (size_t)(k0 + r) * C + c * 256 + c4 * 4);
    ushort4 u;
    u.x = f2b(v.x); u.y = f2b(v.y); u.z = f2b(v.z); u.w = f2b(v.w);
    *(ushort4*)&ts[r * 264 + ((c4 ^ ((r >> 3) & 7)) << 2)] = u;
  }
  __syncthreads();
  #pragma unroll
  for (int s = 0; s < 4; s++) {
    const int idx = s * 256 + tid;          // 0..1023 = 256 n x 4 kc
    const int n = idx >> 2, kc = idx & 3;
    ushort o[8];
    #pragma unroll
    for (int j = 0; j < 8; j++)
      o[j] = ts[(kc * 8 + j) * 264 + (((n >> 2) ^ kc) << 2) + (n & 3)];
    *(uint4*)&dst[tp_idx(c * 256 + n, k0 + kc * 8, KT)] = *(uint4*)o;
  }
}

// ---------------------------------------------------------------------------
// MEGA-PREP flat dispatch (heavy transpose blocks FIRST):
//   [0,6144)        W1/W3/W2: 48 slices x 32 bands x 4 chunks
//   [6144,6400)     sW1 (R=1024,C=2048): 32 bands x 8 chunks
//   [6400,6656)     sW2 (R=2048,C=1024): 64 bands x 4 chunks
//   [6656,7680)     gate: wave-parallel softmax+top2, 1 wave = 1 token
//   [7680,8192)     cast emb->etp, x->xtp
// ---------------------------------------------------------------------------
#define PREP_BLOCKS 8192
__launch_bounds__(256, 4)
__global__ void prep(const float* __restrict__ emb, const float* __restrict__ x_,
                     const float* __restrict__ gw,
                     const float* __restrict__ W1, const float* __restrict__ W3,
                     const float* __restrict__ W2,
                     const float* __restrict__ sW1, const float* __restrict__ sW2,
                     ushort* __restrict__ etp, ushort* __restrict__ xtp,
                     ushort* __restrict__ w1tp, ushort* __restrict__ w3tp,
                     ushort* __restrict__ w2tp,
                     ushort* __restrict__ sw1tp, ushort* __restrict__ sw2tp,
                     int* __restrict__ eA, int* __restrict__ eB,
                     float* __restrict__ wA, float* __restrict__ wB)
{
  __shared__ ushort ts[32 * 264];   // 16896 B -> 8 blocks/CU
  const int b = blockIdx.x;
  const int t = threadIdx.x;

  if (b < 6656) {
    const float* src; ushort* dst; int R, C, band, chunk;
    if (b < 6144) {
      const int z = b >> 7, rem = b & 127;       // slice 0..47
      band = rem >> 2; chunk = rem & 3;          // 32 bands x 4 chunks
      const int e = z & 15;
      src = ((z < 16) ? W1 : (z < 32) ? W3 : W2) + ((size_t)e << 20);
      dst = ((z < 16) ? w1tp : (z < 32) ? w3tp : w2tp) + ((size_t)e << 20);
      R = 1024; C = 1024;
    } else if (b < 6400) {
      const int i = b - 6144; band = i >> 3; chunk = i & 7;   // 32 bands x 8
      src = sW1; dst = sw1tp; R = 1024; C = 2048;
    } else {
      const int i = b - 6400; band = i >> 2; chunk = i & 3;   // 64 bands x 4
      src = sW2; dst = sw2tp; R = 2048; C = 1024;
    }
    tr_chunk(src, dst, R, C, band, chunk, t, ts);
  } else if (b < 7680) {
    // ---- gate: 1 wave = 1 token; all loads 1KB-contiguous per instruction.
    const int w = t >> 6, lane = t & 63;
    const int tok = (b - 6656) * 4 + w;
    const float* er = emb + (size_t)tok * DIM + lane * 4;
    const float4 a0 = *(const float4*)(er);
    const float4 a1 = *(const float4*)(er + 256);
    const float4 a2 = *(const float4*)(er + 512);
    const float4 a3 = *(const float4*)(er + 768);
    float pe[NEXP];
    #pragma unroll
    for (int e = 0; e < NEXP; e++) {
      const float* gr = gw + (size_t)e * DIM + lane * 4;
      const float4 g0 = *(const float4*)(gr);
      const float4 g1 = *(const float4*)(gr + 256);
      const float4 g2 = *(const float4*)(gr + 512);
      const float4 g3 = *(const float4*)(gr + 768);
      float p = a0.x * g0.x + a0.y * g0.y + a0.z * g0.z + a0.w * g0.w;
      p += a1.x * g1.x + a1.y * g1.y + a1.z * g1.z + a1.w * g1.w;
      p += a2.x * g2.x + a2.y * g2.y + a2.z * g2.z + a2.w * g2.w;
      p += a3.x * g3.x + a3.y * g3.y + a3.z * g3.z + a3.w * g3.w;
      pe[e] = p;
    }
    #pragma unroll
    for (int e = 0; e < NEXP; e++) {
      float v = pe[e];
      v += __shfl_xor(v, 1);  v += __shfl_xor(v, 2);
      v += __shfl_xor(v, 4);  v += __shfl_xor(v, 8);
      v += __shfl_xor(v, 16); v += __shfl_xor(v, 32);
      pe[e] = v;
    }
    if (lane == 0) {
      float m1 = pe[0];
      #pragma unroll
      for (int j = 1; j < NEXP; j++) m1 = fmaxf(m1, pe[j]);
      float sum = 0.f;
      #pragma unroll
      for (int j = 0; j < NEXP; j++) sum += __expf(pe[j] - m1);
      int i0 = 0; float b0 = pe[0];
      #pragma unroll
      for (int j = 1; j < NEXP; j++) if (pe[j] > b0) { b0 = pe[j]; i0 = j; }
      int i1 = -1; float b1 = -3.402823466e38f;
      #pragma unroll
      for (int j = 0; j < NEXP; j++) if (j != i0 && pe[j] > b1) { b1 = pe[j]; i1 = j; }
      const float inv = 1.0f / sum;
      eA[tok] = i0; wA[tok] = __expf(b0 - m1) * inv;
      eB[tok] = i1; wB[tok] = __expf(b1 - m1) * inv;
    }
  } else {
    // ---------------- cast emb/x -> TP bf16 ----------------
    const int NC = (T_TOK * DIM) / 8;
    const int c0 = (b - 7680) * 256 + t;
    for (int c = c0; c < 2 * NC; c += 512 * 256) {
      const bool isE = c < NC;
      const int g = (isE ? c : c - NC) << 3;
      const float* src = isE ? emb : x_;
      const float4 v0 = *(const float4*)(src + g);
      const float4 v1 = *(const float4*)(src + g + 4);
      ushort tt[8];
      tt[0] = f2b(v0.x); tt[1] = f2b(v0.y); tt[2] = f2b(v0.z); tt[3] = f2b(v0.w);
      tt[4] = f2b(v1.x); tt[5] = f2b(v1.y); tt[6] = f2b(v1.z); tt[7] = f2b(v1.w);
      const int row = g >> 10, col = g & 1023;
      ushort* dst = isE ? etp : xtp;
      *(uint4*)&dst[tp_idx(row, col, 32)] = *(uint4*)tt;
    }
  }
}

// ---------------------------------------------------------------------------
// Build per-expert compact lists from per-token top-2 (deterministic).
// ---------------------------------------------------------------------------
__global__ void build_lists(const int* __restrict__ eA, const int* __restrict__ eB,
                            const float* __restrict__ wA, const float* __restrict__ wB,
                            int* __restrict__ cnt, int* __restrict__ list,
                            float* __restrict__ wl)
{
  const int e = blockIdx.x;
  __shared__ int wsum[4];
  __shared__ int sbase;
  const int tid = threadIdx.x;
  const int lane = tid & 63, wv = tid >> 6;
  if (tid == 0) sbase = 0;
  __syncthreads();
  for (int r = 0; r < 16; r++) {
    const int tk = r * 256 + tid;
    const int a = eA[tk], bb = eB[tk];
    const bool m = (a == e) || (bb == e);
    const float w = (a == e) ? wA[tk] : wB[tk];
    const unsigned long long bal = __ballot(m);
    const int pw = __popcll(bal & ((1ULL << lane) - 1ULL));
    if (lane == 63) wsum[wv] = pw + (m ? 1 : 0);
    __syncthreads();
    int base = sbase;
    for (int k = 0; k < wv; k++) base += wsum[k];
    if (m) {
      const int pos = base + pw;
      list[e * T_TOK + pos] = tk;
      wl[e * T_TOK + pos] = w;
    }
    __syncthreads();
    if (tid == 0) sbase += wsum[0] + wsum[1] + wsum[2] + wsum[3];
    __syncthreads();
  }
  if (tid == 0) cnt[e] = sbase;
}

// offp[e] = 128-aligned prefix sum; offp[17] = #m-tiles; tbl[2*mt] = {e, row0}
__global__ void scan_offs(const int* __restrict__ cnt, int* __restrict__ offp,
                          int* __restrict__ tbl)
{
  if (blockIdx.x == 0 && threadIdx.x == 0) {
    int a = 0, nm = 0;
    for (int e = 0; e < NEXP; e++) {
      offp[e] = a;
      const int c = (cnt[e] + 127) & ~127;
      for (int r = 0; r < c; r += 128) { tbl[2 * nm] = e; tbl[2 * nm + 1] = a + r; nm++; }
      a += c;
    }
    offp[NEXP] = a;
    offp[NEXP + 1] = nm;
  }
}

// ---------------------------------------------------------------------------
// Stage 1, flat grid: b < 512 -> shared front (hs TP); else routed SwiGLU
// front (h TP). Routed A is token-GATHERED in staging: per-lane source =
// token tile + srcA(row, cl) -- each row's 4 chunks are one 64B line, so
// gather reads coalesce like a verbatim copy. Pad rows clamp to a valid
// token; pads masked downstream by rowl<ce.
// ---------------------------------------------------------------------------
__launch_bounds__(256, 3)
__global__ void stage1(const ushort* __restrict__ etp, const ushort* __restrict__ xtp,
                       const ushort* __restrict__ w1tp, const ushort* __restrict__ w3tp,
                       const ushort* __restrict__ sw1tp,
                       const float* __restrict__ B1, const float* __restrict__ B3,
                       const float* __restrict__ sB1,
                       const int* __restrict__ cnt, const int* __restrict__ offp,
                       const int* __restrict__ tbl, const int* __restrict__ list,
                       ushort* __restrict__ h_tp, ushort* __restrict__ hs_tp)
{
  __shared__ ushort As[8192], Bs1[8192], Bs3[8192];
  const int tid = threadIdx.x;
  const int lane = tid & 63, w = tid >> 6;
  const int wm = w & 1, wn = w >> 1;
  const int quad = lane >> 4, lr = lane & 15;
  const int rd0 = w * 32 + (lane >> 2), rd1 = rd0 + 16;
  const int cl = (lane & 3) ^ ((lane >> 3) & 3);   // logical chunk this lane stages
  const int dl = w * 1024 + lane * 8;              // verbatim per-lane offset
  const int b = blockIdx.x;

  f4_t acc1[4][4], acc3[4][4];
  const f4_t fz = {0.f, 0.f, 0.f, 0.f};
  #pragma unroll
  for (int i = 0; i < 4; i++)
    #pragma unroll
    for (int j = 0; j < 4; j++) { acc1[i][j] = fz; acc3[i][j] = fz; }

  if (b < 512) {                       // ---- shared expert front: all real
    const int m0 = (b >> 4) << 7;
    const int n0 = (b & 15) << 7;
    const ushort* aT = etp + (((size_t)(m0 >> 7) * 32) << 12);
    const ushort* bT = sw1tp + (((size_t)(n0 >> 7) * 32) << 12);
    mfma_tp<false>(aT + dl, aT + dl + 512, bT + dl, nullptr,
                   32, As, Bs1, Bs3, acc1, acc3, tid);
    #pragma unroll
    for (int mi = 0; mi < 4; mi++) {
      #pragma unroll
      for (int r = 0; r < 4; r++) {
        const int row = m0 + wm * 64 + mi * 16 + quad * 4 + r;
        #pragma unroll
        for (int ni = 0; ni < 4; ni++) {
          const int col = n0 + wn * 64 + ni * 16 + lr;
          const float v = acc1[mi][ni][r] + sB1[col];
          const float sg = 1.0f / (1.0f + __expf(-v));
          hs_tp[tp_idx(row, col, 64)] = f2b(v * sg);
        }
      }
    }
  } else {                             // ---- routed SwiGLU front
    const int t = b - 512;
    const int mt = t >> 3;
    if (mt >= offp[NEXP + 1]) return;
    const int n0 = (t & 7) << 7;
    const int e = tbl[2 * mt], row0 = tbl[2 * mt + 1];
    const int ce = cnt[e];
    const int s0 = row0 - offp[e];
    const ushort* src = (e < NIN) ? xtp : etp;
    int sa = s0 + rd0; if (sa >= ce) sa = ce - 1;
    int sb = s0 + rd1; if (sb >= ce) sb = ce - 1;
    const int tokA = list[e * T_TOK + sa];
    const int tokB = list[e * T_TOK + sb];
    const ushort* pA0 = src + (((size_t)(tokA >> 7) * 32) << 12) + srcA(tokA & 127, cl);
    const ushort* pA1 = src + (((size_t)(tokB >> 7) * 32) << 12) + srcA(tokB & 127, cl);
    const ushort* b1T = w1tp + ((size_t)e << 20) + (((size_t)(n0 >> 7) * 32) << 12);
    const ushort* b3T = w3tp + ((size_t)e << 20) + (((size_t)(n0 >> 7) * 32) << 12);
    mfma_tp<true>(pA0, pA1, b1T + dl, b3T + dl,
                  32, As, Bs1, Bs3, acc1, acc3, tid);
    #pragma unroll
    for (int mi = 0; mi < 4; mi++) {
      #pragma unroll
      for (int r = 0; r < 4; r++) {
        const int grow = row0 + wm * 64 + mi * 16 + quad * 4 + r;
        #pragma unroll
        for (int ni = 0; ni < 4; ni++) {
          const int col = n0 + wn * 64 + ni * 16 + lr;
          const float v1 = acc1[mi][ni][r] + B1[e * HID + col];
          const float v3 = acc3[mi][ni][r] + B3[e * HID + col];
          const float sg = 1.0f / (1.0f + __expf(-v1));
          h_tp[tp_idx(grow, col, 32)] = f2b(v1 * sg * v3);
        }
      }
    }
  }
}

// ---------------------------------------------------------------------------
// Stage 2, flat grid: b < 256 -> shared back; else routed back. Both
// atomicAdd into zero-inited y.
// ---------------------------------------------------------------------------
__launch_bounds__(256, 4)
__global__ void stage2(const ushort* __restrict__ h_tp, const ushort* __restrict__ hs_tp,
                       const ushort* __restrict__ w2tp, const ushort* __restrict__ sw2tp,
                       const float* __restrict__ B2, const float* __restrict__ sB2,
                       const int* __restrict__ cnt, const int* __restrict__ offp,
                       const int* __restrict__ tbl, const int* __restrict__ list,
                       const float* __restrict__ wl, float* __restrict__ y)
{
  __shared__ ushort As[8192], Bs[8192];
  const int tid = threadIdx.x;
  const int lane = tid & 63, w = tid >> 6;
  const int wm = w & 1, wn = w >> 1;
  const int quad = lane >> 4, lr = lane & 15;
  const int dl = w * 1024 + lane * 8;
  const int b = blockIdx.x;

  f4_t acc[4][4];
  const f4_t fz = {0.f, 0.f, 0.f, 0.f};
  #pragma unroll
  for (int i = 0; i < 4; i++)
    #pragma unroll
    for (int j = 0; j < 4; j++) acc[i][j] = fz;

  if (b < 256) {                       // ---- shared expert back (K=2048)
    const int m0 = (b >> 3) << 7;
    const int n0 = (b & 7) << 7;
    const ushort* aT = hs_tp + (((size_t)(m0 >> 7) * 64) << 12);
    const ushort* bT = sw2tp + (((size_t)(n0 >> 7) * 64) << 12);
    mfma_tp<false>(aT + dl, aT + dl + 512, bT + dl, nullptr,
                   64, As, Bs, Bs, acc, acc, tid);
    #pragma unroll
    for (int mi = 0; mi < 4; mi++) {
      #pragma unroll
      for (int r = 0; r < 4; r++) {
        const int row = m0 + wm * 64 + mi * 16 + quad * 4 + r;
        float* yr = y + (size_t)row * DIM;
        #pragma unroll
        for (int ni = 0; ni < 4; ni++) {
          const int col = n0 + wn * 64 + ni * 16 + lr;
          atomicAdd(&yr[col], acc[mi][ni][r] + sB2[col]);
        }
      }
    }
  } else {                             // ---- routed back (K=1024)
    const int t = b - 256;
    const int mt = t >> 3;
    if (mt >= offp[NEXP + 1]) return;
    const int n0 = (t & 7) << 7;
    const int e = tbl[2 * mt], row0 = tbl[2 * mt + 1];
    const int ce = cnt[e];
    const int s0 = row0 - offp[e];
    const ushort* aT = h_tp + (((size_t)(row0 >> 7) * 32) << 12);
    const ushort* bT = w2tp + ((size_t)e << 20) + (((size_t)(n0 >> 7) * 32) << 12);
    mfma_tp<false>(aT + dl, aT + dl + 512, bT + dl, nullptr,
                   32, As, Bs, Bs, acc, acc, tid);
    #pragma unroll
    for (int mi = 0; mi < 4; mi++) {
      #pragma unroll
      for (int r = 0; r < 4; r++) {
        const int rowl = s0 + wm * 64 + mi * 16 + quad * 4 + r;
        if (rowl < ce) {
          const int tok = list[e * T_TOK + rowl];
          const float wgt = wl[e * T_TOK + rowl];
          float* yr = y + (size_t)tok * DIM;
          #pragma unroll
          for (int ni = 0; ni < 4; ni++) {
            const int col = n0 + wn * 64 + ni * 16 + lr;
            atomicAdd(&yr[col], wgt * (acc[mi][ni][r] + B2[e * DIM + col]));
          }
        }
      }
    }
  }
}

// ---------------------------------------------------------------------------
// Launch
// ---------------------------------------------------------------------------
extern "C" void kernel_launch(void* const* d_in, const int* in_sizes, int n_in,
                              void* d_out, int out_size, void* d_ws, size_t ws_size,
                              hipStream_t stream)
{
  const float* emb = (const float*)d_in[0];
  const float* x   = (const float*)d_in[1];
  const float* gw  = (const float*)d_in[2];
  const float* W1  = (const float*)d_in[3];
  const float* B1  = (const float*)d_in[4];
  const float* W2  = (const float*)d_in[5];
  const float* B2  = (const float*)d_in[6];
  const float* W3  = (const float*)d_in[7];
  const float* B3  = (const float*)d_in[8];
  const float* sW1 = (const float*)d_in[9];
  const float* sB1 = (const float*)d_in[10];
  const float* sW2 = (const float*)d_in[11];
  const float* sB2 = (const float*)d_in[12];
  float* y = (float*)d_out;

  char* ws = (char*)d_ws;
  const size_t MB = 1024ULL * 1024ULL;
  ushort* xtp   = (ushort*)(ws + 0);        // x TP (KT=32)
  ushort* etp   = (ushort*)(ws + 16 * MB);  // emb TP (KT=32)
  ushort* w1tp  = (ushort*)(ws + 24 * MB);  // [16] x TP [1024n][1024k]
  ushort* w3tp  = (ushort*)(ws + 56 * MB);
  ushort* w2tp  = (ushort*)(ws + 88 * MB);  // [16] x TP [1024n][1024k]
  ushort* sw1tp = (ushort*)(ws + 120 * MB); // TP [2048n][1024k]
  ushort* sw2tp = (ushort*)(ws + 124 * MB); // TP [1024n][2048k]
  ushort* h_tp  = (ushort*)(ws + 148 * MB); // routed hidden, TP, <=10240 rows
  ushort* hs_tp = (ushort*)(ws + 168 * MB); // shared hidden, TP [4096][2048]
  int*   cnt    = (int*)(ws + 184 * MB);    // [16]
  int*   offp   = cnt + 16;                 // [18]  (offp[17] = #m-tiles)
  int*   tbl    = offp + 18;                // [2*MT_MAX]
  int*   list   = (int*)(ws + 184 * MB + 1024);            // [16][4096]
  float* wl     = (float*)(ws + 184 * MB + 1024 + 262144); // [16][4096]
  int*   eA     = (int*)(ws + 185 * MB);    // [4096]
  int*   eB     = eA + T_TOK;
  float* wA     = (float*)(eB + T_TOK);
  float* wB     = wA + T_TOK;

  hipMemsetAsync(y, 0, (size_t)T_TOK * DIM * sizeof(float), stream);
  prep<<<PREP_BLOCKS, 256, 0, stream>>>(emb, x, gw, W1, W3, W2, sW1, sW2,
                                        etp, xtp, w1tp, w3tp, w2tp,
                                        sw1tp, sw2tp, eA, eB, wA, wB);
  build_lists<<<NEXP, 256, 0, stream>>>(eA, eB, wA, wB, cnt, list, wl);
  scan_offs<<<1, 64, 0, stream>>>(cnt, offp, tbl);
  stage1<<<512 + MT_MAX * 8, 256, 0, stream>>>(etp, xtp, w1tp, w3tp, sw1tp,
                                               B1, B3, sB1, cnt, offp, tbl, list,
                                               h_tp, hs_tp);
  stage2<<<256 + MT_MAX * 8, 256, 0, stream>>>(h_tp, hs_tp, w2tp, sw2tp, B2, sB2,
                                               cnt, offp, tbl, list, wl, y);
}